// Round 1
// baseline (125.547 us; speedup 1.0000x reference)
//
#include <hip/hip_runtime.h>

typedef __bf16 bf16x8 __attribute__((ext_vector_type(8)));
typedef float f32x4 __attribute__((ext_vector_type(4)));

// Problem constants
// B=4, Cin=64, Cout=64, H=W=128, K=3, PAD=1, KK=9, offset channels=18

// ---------------- Kernel 1: offset conv (f32, exact) ----------------
// offs[b][ch][h][w], ch = 2*k + {0:dy,1:dx}
__global__ __launch_bounds__(256) void k_offset_conv(
    const float* __restrict__ x, const float* __restrict__ ow,
    const float* __restrict__ ob, float* __restrict__ offs) {
  int idx = blockIdx.x * 256 + threadIdx.x;   // over B*H*W = 65536
  int w = idx & 127;
  int h = (idx >> 7) & 127;
  int b = idx >> 14;
  float acc[18];
#pragma unroll
  for (int co = 0; co < 18; ++co) acc[co] = ob[co];
  for (int ci = 0; ci < 64; ++ci) {
    const float* xb = x + ((b * 64 + ci) * 128) * 128;
    float xr[9];
#pragma unroll
    for (int r = 0; r < 3; ++r) {
      int hh = h - 1 + r;
      bool hv = (unsigned)hh < 128u;
#pragma unroll
      for (int cc = 0; cc < 3; ++cc) {
        int ww = w - 1 + cc;
        bool v = hv && ((unsigned)ww < 128u);
        xr[r * 3 + cc] = v ? xb[hh * 128 + ww] : 0.0f;
      }
    }
    const float* wp = ow + ci * 9;  // ow[(co*64+ci)*9 + t]
#pragma unroll
    for (int co = 0; co < 18; ++co) {
#pragma unroll
      for (int t = 0; t < 9; ++t)
        acc[co] = fmaf(xr[t], wp[co * 576 + t], acc[co]);
    }
  }
#pragma unroll
  for (int co = 0; co < 18; ++co)
    offs[((b * 18 + co) * 128 + h) * 128 + w] = acc[co];
}

// ---------------- Kernel 2: x (NCHW f32) -> x_t (NHWC bf16) ----------------
__global__ __launch_bounds__(256) void k_xt(const float* __restrict__ x,
                                            __bf16* __restrict__ xt) {
  __shared__ float tile[64 * 129];
  int b = blockIdx.x >> 7;
  int y = blockIdx.x & 127;
  int t = threadIdx.x;
#pragma unroll
  for (int it = 0; it < 32; ++it) {
    int r = it * 256 + t;           // 8192 elems: 64c x 128w
    int c = r >> 7, xw = r & 127;
    tile[c * 129 + xw] = x[((b * 64 + c) * 128 + y) * 128 + xw];
  }
  __syncthreads();
#pragma unroll
  for (int it = 0; it < 32; ++it) {
    int r = it * 256 + t;
    int xw = r >> 6, c = r & 63;
    xt[((b * 128 + y) * 128 + xw) * 64 + c] = (__bf16)tile[c * 129 + xw];
  }
}

// ---------------- Kernel 3: weight f32 (O,C,3,3) -> Wb bf16 [k][o][c] ----------------
__global__ __launch_bounds__(256) void k_wprep(const float* __restrict__ wt,
                                               __bf16* __restrict__ wb) {
  int i = blockIdx.x * 256 + threadIdx.x;  // 9*64*64 = 36864
  int k = i >> 12;
  int rem = i & 4095;
  int o = rem >> 6;
  int c = rem & 63;
  wb[i] = (__bf16)wt[(o * 64 + c) * 9 + k];
}

// ---------------- Kernel 4: fused sampling + bf16 MFMA GEMM ----------------
// grid: 1024 blocks = (2 wtiles) x (128 h) x (4 b); 256 threads (4 waves)
// out tile: 64 o x 64 pixels
__global__ __launch_bounds__(256) void k_main(
    const __bf16* __restrict__ xt, const float* __restrict__ offs,
    const __bf16* __restrict__ wb, const float* __restrict__ bias,
    float* __restrict__ out) {
  __shared__ __bf16 Wk[64 * 72];  // [o][c], stride 72 to stagger banks
  __shared__ __bf16 S[64 * 72];   // [pix][c]

  int t = threadIdx.x;
  int wtile = blockIdx.x & 1;
  int h = (blockIdx.x >> 1) & 127;
  int b = blockIdx.x >> 8;
  int w0 = wtile * 64;

  int pix = t >> 2;        // 0..63
  int cg = t & 3;          // c-group of 16
  int w = w0 + pix;

  int lane = t & 63;
  int wid = t >> 6;
  int wo = (wid >> 1) * 32;  // wave o-base
  int wp = (wid & 1) * 32;   // wave pix-base

  f32x4 acc[2][2];
#pragma unroll
  for (int i = 0; i < 2; ++i)
#pragma unroll
    for (int j = 0; j < 2; ++j) acc[i][j] = f32x4{0.f, 0.f, 0.f, 0.f};

  for (int k = 0; k < 9; ++k) {
    // ---- stage W_k: wb[k*4096 + o*64 + c] -> Wk[o*72 + c] ----
    {
      const bf16x8* src = (const bf16x8*)(wb + k * 4096);
#pragma unroll
      for (int r = 0; r < 2; ++r) {
        int idx8 = r * 256 + t;
        int o = idx8 >> 3;
        int c8 = (idx8 & 7) * 8;
        bf16x8 v = src[idx8];
        *(bf16x8*)&Wk[o * 72 + c8] = v;
      }
    }
    // ---- compute sampled tile S[pix][c] for this k ----
    {
      int ki = k / 3, kj = k % 3;
      float dy = offs[((b * 18 + 2 * k) * 128 + h) * 128 + w];
      float dx = offs[((b * 18 + 2 * k + 1) * 128 + h) * 128 + w];
      float py = dy + (float)(h + ki - 1);
      float px = dx + (float)(w + kj - 1);
      float fy = floorf(py), fx = floorf(px);
      float ly = py - fy, lx = px - fx;
      int y0 = (int)fy, x0 = (int)fx;
      int y1 = y0 + 1, x1 = x0 + 1;
      bool vy0 = (unsigned)y0 < 128u, vy1 = (unsigned)y1 < 128u;
      bool vx0 = (unsigned)x0 < 128u, vx1 = (unsigned)x1 < 128u;
      float w00 = (vy0 && vx0) ? (1.f - ly) * (1.f - lx) : 0.f;
      float w01 = (vy0 && vx1) ? (1.f - ly) * lx : 0.f;
      float w10 = (vy1 && vx0) ? ly * (1.f - lx) : 0.f;
      float w11 = (vy1 && vx1) ? ly * lx : 0.f;
      int yc0 = min(max(y0, 0), 127), yc1 = min(max(y1, 0), 127);
      int xc0 = min(max(x0, 0), 127), xc1 = min(max(x1, 0), 127);
      const __bf16* xb = xt + (size_t)(b * 128) * 128 * 64 + cg * 16;
      const bf16x8* p00 = (const bf16x8*)(xb + (yc0 * 128 + xc0) * 64);
      const bf16x8* p01 = (const bf16x8*)(xb + (yc0 * 128 + xc1) * 64);
      const bf16x8* p10 = (const bf16x8*)(xb + (yc1 * 128 + xc0) * 64);
      const bf16x8* p11 = (const bf16x8*)(xb + (yc1 * 128 + xc1) * 64);
      bf16x8 a00 = p00[0], b00 = p00[1];
      bf16x8 a01 = p01[0], b01 = p01[1];
      bf16x8 a10 = p10[0], b10 = p10[1];
      bf16x8 a11 = p11[0], b11 = p11[1];
      bf16x8 o0, o1;
#pragma unroll
      for (int j = 0; j < 8; ++j) {
        float s0 = w00 * (float)a00[j] + w01 * (float)a01[j] +
                   w10 * (float)a10[j] + w11 * (float)a11[j];
        float s1 = w00 * (float)b00[j] + w01 * (float)b01[j] +
                   w10 * (float)b10[j] + w11 * (float)b11[j];
        o0[j] = (__bf16)s0;
        o1[j] = (__bf16)s1;
      }
      *(bf16x8*)&S[pix * 72 + cg * 16] = o0;
      *(bf16x8*)&S[pix * 72 + cg * 16 + 8] = o1;
    }
    __syncthreads();
    // ---- MFMA: acc += W_k[o][c] * S[c][pix] ----
    {
      int row = lane & 15;
      int quad = lane >> 4;
#pragma unroll
      for (int ks = 0; ks < 2; ++ks) {
        int c0 = ks * 32 + quad * 8;
        bf16x8 afr[2], bfr[2];
#pragma unroll
        for (int mi = 0; mi < 2; ++mi)
          afr[mi] = *(const bf16x8*)&Wk[(wo + mi * 16 + row) * 72 + c0];
#pragma unroll
        for (int ni = 0; ni < 2; ++ni)
          bfr[ni] = *(const bf16x8*)&S[(wp + ni * 16 + row) * 72 + c0];
#pragma unroll
        for (int mi = 0; mi < 2; ++mi)
#pragma unroll
          for (int ni = 0; ni < 2; ++ni)
            acc[mi][ni] = __builtin_amdgcn_mfma_f32_16x16x32_bf16(
                afr[mi], bfr[ni], acc[mi][ni], 0, 0, 0);
      }
    }
    __syncthreads();
  }
  // ---- epilogue: C/D layout col=lane&15 (pix), row=(lane>>4)*4+reg (o) ----
  {
    int col = lane & 15;
    int qr = (lane >> 4) * 4;
#pragma unroll
    for (int mi = 0; mi < 2; ++mi) {
#pragma unroll
      for (int ni = 0; ni < 2; ++ni) {
#pragma unroll
        for (int r = 0; r < 4; ++r) {
          int o = wo + mi * 16 + qr + r;
          int pw = w0 + wp + ni * 16 + col;
          out[((b * 64 + o) * 128 + h) * 128 + pw] = acc[mi][ni][r] + bias[o];
        }
      }
    }
  }
}

extern "C" void kernel_launch(void* const* d_in, const int* in_sizes, int n_in,
                              void* d_out, int out_size, void* d_ws,
                              size_t ws_size, hipStream_t stream) {
  const float* x = (const float*)d_in[0];       // (4,64,128,128)
  const float* ow = (const float*)d_in[1];      // (18,64,3,3)
  const float* ob = (const float*)d_in[2];      // (18,)
  const float* wt = (const float*)d_in[3];      // (64,64,3,3)
  const float* bias = (const float*)d_in[4];    // (64,)
  float* out = (float*)d_out;                   // (4,64,128,128)

  char* ws = (char*)d_ws;
  float* offs = (float*)ws;                          // 4*18*128*128*4 = 4718592 B
  __bf16* xt = (__bf16*)(ws + 4718592);              // 4*128*128*64*2 = 8388608 B
  __bf16* wb = (__bf16*)(ws + 4718592 + 8388608);    // 9*64*64*2 = 73728 B

  k_offset_conv<<<256, 256, 0, stream>>>(x, ow, ob, offs);
  k_xt<<<512, 256, 0, stream>>>(x, xt);
  k_wprep<<<144, 256, 0, stream>>>(wt, wb);
  k_main<<<1024, 256, 0, stream>>>(xt, offs, wb, bias, out);
}

// Round 2
// 66.450 us; speedup vs baseline: 1.8894x; 1.8894x over previous
//
#include <hip/hip_runtime.h>

typedef __bf16 bf16x8 __attribute__((ext_vector_type(8)));
typedef float f32x4 __attribute__((ext_vector_type(4)));

// Problem constants: B=4, Cin=64, Cout=64, H=W=128, K=3, PAD=1, KK=9

// ---------------- Kernel 2: x (NCHW f32) -> x_t (NHWC bf16) ----------------
__global__ __launch_bounds__(256) void k_xt(const float* __restrict__ x,
                                            __bf16* __restrict__ xt) {
  __shared__ float tile[64 * 129];
  int b = blockIdx.x >> 7;
  int y = blockIdx.x & 127;
  int t = threadIdx.x;
#pragma unroll
  for (int it = 0; it < 32; ++it) {
    int r = it * 256 + t;           // 8192 elems: 64c x 128w
    int c = r >> 7, xw = r & 127;
    tile[c * 129 + xw] = x[((b * 64 + c) * 128 + y) * 128 + xw];
  }
  __syncthreads();
#pragma unroll
  for (int it = 0; it < 32; ++it) {
    int r = it * 256 + t;
    int xw = r >> 6, c = r & 63;
    xt[((b * 128 + y) * 128 + xw) * 64 + c] = (__bf16)tile[c * 129 + xw];
  }
}

// ---------------- Kernel 3: weight f32 (O,C,3,3) -> Wb bf16 [k][o][c] ----------------
__global__ __launch_bounds__(256) void k_wprep(const float* __restrict__ wt,
                                               __bf16* __restrict__ wb) {
  int i = blockIdx.x * 256 + threadIdx.x;  // 9*64*64 = 36864
  int k = i >> 12;
  int rem = i & 4095;
  int o = rem >> 6;
  int c = rem & 63;
  wb[i] = (__bf16)wt[(o * 64 + c) * 9 + k];
}

// ------------- Kernel 3b: offset weights f32 (18,64,3,3) -> bf16 [k][32pad][c] -------------
__global__ __launch_bounds__(256) void k_owprep(const float* __restrict__ ow,
                                                __bf16* __restrict__ owb) {
  int i = blockIdx.x * 256 + threadIdx.x;  // 9*32*64 = 18432
  int k = i >> 11;
  int rem = i & 2047;
  int o = rem >> 6;
  int c = rem & 63;
  float v = (o < 18) ? ow[(o * 64 + c) * 9 + k] : 0.0f;
  owb[i] = (__bf16)v;
}

// ---------------- Kernel 1': offset conv via bf16 MFMA ----------------
// grid: 1024 blocks = (2 wtiles) x (128 h) x (4 b); 256 threads (4 waves)
// out: offs[b][18][h][w]; M=18 (padded 32), N=64 pix, K=576
// No LDS, no barriers: A-frags from owb (L2-hot), B-frags from xt rows (L1/L2-hot).
__global__ __launch_bounds__(256) void k_offset_mfma(
    const __bf16* __restrict__ xt, const __bf16* __restrict__ owb,
    const float* __restrict__ ob, float* __restrict__ offs) {
  int t = threadIdx.x;
  int wtile = blockIdx.x & 1;
  int h = (blockIdx.x >> 1) & 127;
  int b = blockIdx.x >> 8;
  int w0 = wtile * 64;

  int lane = t & 63, wid = t >> 6;
  int wo = (wid >> 1) * 16;  // o-tile base: 0 or 16
  int wp = (wid & 1) * 32;   // pixel base: 0 or 32
  int row = lane & 15, quad = lane >> 4;

  f32x4 acc[2];
  acc[0] = f32x4{0.f, 0.f, 0.f, 0.f};
  acc[1] = f32x4{0.f, 0.f, 0.f, 0.f};
  bf16x8 zero = {};

  const __bf16* xb = xt + (size_t)b * 128 * 128 * 64;

  for (int k = 0; k < 9; ++k) {
    int ki = k / 3, kj = k % 3;
    int hh = h + ki - 1;
    if ((unsigned)hh >= 128u) continue;  // whole k-tap row is zero -> skip
    bf16x8 afr[2];
#pragma unroll
    for (int ks = 0; ks < 2; ++ks)
      afr[ks] =
          *(const bf16x8*)(owb + k * 2048 + (wo + row) * 64 + ks * 32 + quad * 8);
#pragma unroll
    for (int n = 0; n < 2; ++n) {
      int gx = w0 + wp + n * 16 + row + kj - 1;
      bool oob = (unsigned)gx >= 128u;
      int gxc = min(max(gx, 0), 127);
      const __bf16* p = xb + (hh * 128 + gxc) * 64 + quad * 8;
      bf16x8 bfr0 = *(const bf16x8*)(p);
      bf16x8 bfr1 = *(const bf16x8*)(p + 32);
      if (oob) { bfr0 = zero; bfr1 = zero; }
      acc[n] = __builtin_amdgcn_mfma_f32_16x16x32_bf16(afr[0], bfr0, acc[n], 0, 0, 0);
      acc[n] = __builtin_amdgcn_mfma_f32_16x16x32_bf16(afr[1], bfr1, acc[n], 0, 0, 0);
    }
  }
  // epilogue: C/D layout col=lane&15 (pix), row=(lane>>4)*4+reg (o)
  int col = lane & 15, qr = quad * 4;
#pragma unroll
  for (int n = 0; n < 2; ++n) {
#pragma unroll
    for (int r = 0; r < 4; ++r) {
      int co = wo + qr + r;
      if (co < 18) {
        int pw = w0 + wp + n * 16 + col;
        offs[((b * 18 + co) * 128 + h) * 128 + pw] = acc[n][r] + ob[co];
      }
    }
  }
}

// ---------------- Kernel 4: fused sampling + bf16 MFMA GEMM ----------------
// grid: 1024 blocks = (2 wtiles) x (128 h) x (4 b); 256 threads (4 waves)
// out tile: 64 o x 64 pixels
__global__ __launch_bounds__(256) void k_main(
    const __bf16* __restrict__ xt, const float* __restrict__ offs,
    const __bf16* __restrict__ wb, const float* __restrict__ bias,
    float* __restrict__ out) {
  __shared__ __bf16 Wk[64 * 72];  // [o][c], stride 72 to stagger banks
  __shared__ __bf16 S[64 * 72];   // [pix][c]

  int t = threadIdx.x;
  int wtile = blockIdx.x & 1;
  int h = (blockIdx.x >> 1) & 127;
  int b = blockIdx.x >> 8;
  int w0 = wtile * 64;

  int pix = t >> 2;        // 0..63
  int cg = t & 3;          // c-group of 16
  int w = w0 + pix;

  int lane = t & 63;
  int wid = t >> 6;
  int wo = (wid >> 1) * 32;  // wave o-base
  int wp = (wid & 1) * 32;   // wave pix-base

  f32x4 acc[2][2];
#pragma unroll
  for (int i = 0; i < 2; ++i)
#pragma unroll
    for (int j = 0; j < 2; ++j) acc[i][j] = f32x4{0.f, 0.f, 0.f, 0.f};

  for (int k = 0; k < 9; ++k) {
    // ---- stage W_k: wb[k*4096 + o*64 + c] -> Wk[o*72 + c] ----
    {
      const bf16x8* src = (const bf16x8*)(wb + k * 4096);
#pragma unroll
      for (int r = 0; r < 2; ++r) {
        int idx8 = r * 256 + t;
        int o = idx8 >> 3;
        int c8 = (idx8 & 7) * 8;
        bf16x8 v = src[idx8];
        *(bf16x8*)&Wk[o * 72 + c8] = v;
      }
    }
    // ---- compute sampled tile S[pix][c] for this k ----
    {
      int ki = k / 3, kj = k % 3;
      float dy = offs[((b * 18 + 2 * k) * 128 + h) * 128 + w];
      float dx = offs[((b * 18 + 2 * k + 1) * 128 + h) * 128 + w];
      float py = dy + (float)(h + ki - 1);
      float px = dx + (float)(w + kj - 1);
      float fy = floorf(py), fx = floorf(px);
      float ly = py - fy, lx = px - fx;
      int y0 = (int)fy, x0 = (int)fx;
      int y1 = y0 + 1, x1 = x0 + 1;
      bool vy0 = (unsigned)y0 < 128u, vy1 = (unsigned)y1 < 128u;
      bool vx0 = (unsigned)x0 < 128u, vx1 = (unsigned)x1 < 128u;
      float w00 = (vy0 && vx0) ? (1.f - ly) * (1.f - lx) : 0.f;
      float w01 = (vy0 && vx1) ? (1.f - ly) * lx : 0.f;
      float w10 = (vy1 && vx0) ? ly * (1.f - lx) : 0.f;
      float w11 = (vy1 && vx1) ? ly * lx : 0.f;
      int yc0 = min(max(y0, 0), 127), yc1 = min(max(y1, 0), 127);
      int xc0 = min(max(x0, 0), 127), xc1 = min(max(x1, 0), 127);
      const __bf16* xb = xt + (size_t)(b * 128) * 128 * 64 + cg * 16;
      const bf16x8* p00 = (const bf16x8*)(xb + (yc0 * 128 + xc0) * 64);
      const bf16x8* p01 = (const bf16x8*)(xb + (yc0 * 128 + xc1) * 64);
      const bf16x8* p10 = (const bf16x8*)(xb + (yc1 * 128 + xc0) * 64);
      const bf16x8* p11 = (const bf16x8*)(xb + (yc1 * 128 + xc1) * 64);
      bf16x8 a00 = p00[0], b00 = p00[1];
      bf16x8 a01 = p01[0], b01 = p01[1];
      bf16x8 a10 = p10[0], b10 = p10[1];
      bf16x8 a11 = p11[0], b11 = p11[1];
      bf16x8 o0, o1;
#pragma unroll
      for (int j = 0; j < 8; ++j) {
        float s0 = w00 * (float)a00[j] + w01 * (float)a01[j] +
                   w10 * (float)a10[j] + w11 * (float)a11[j];
        float s1 = w00 * (float)b00[j] + w01 * (float)b01[j] +
                   w10 * (float)b10[j] + w11 * (float)b11[j];
        o0[j] = (__bf16)s0;
        o1[j] = (__bf16)s1;
      }
      *(bf16x8*)&S[pix * 72 + cg * 16] = o0;
      *(bf16x8*)&S[pix * 72 + cg * 16 + 8] = o1;
    }
    __syncthreads();
    // ---- MFMA: acc += W_k[o][c] * S[c][pix] ----
    {
      int row = lane & 15;
      int quad = lane >> 4;
#pragma unroll
      for (int ks = 0; ks < 2; ++ks) {
        int c0 = ks * 32 + quad * 8;
        bf16x8 afr[2], bfr[2];
#pragma unroll
        for (int mi = 0; mi < 2; ++mi)
          afr[mi] = *(const bf16x8*)&Wk[(wo + mi * 16 + row) * 72 + c0];
#pragma unroll
        for (int ni = 0; ni < 2; ++ni)
          bfr[ni] = *(const bf16x8*)&S[(wp + ni * 16 + row) * 72 + c0];
#pragma unroll
        for (int mi = 0; mi < 2; ++mi)
#pragma unroll
          for (int ni = 0; ni < 2; ++ni)
            acc[mi][ni] = __builtin_amdgcn_mfma_f32_16x16x32_bf16(
                afr[mi], bfr[ni], acc[mi][ni], 0, 0, 0);
      }
    }
    __syncthreads();
  }
  // ---- epilogue: C/D layout col=lane&15 (pix), row=(lane>>4)*4+reg (o) ----
  {
    int col = lane & 15;
    int qr = (lane >> 4) * 4;
#pragma unroll
    for (int mi = 0; mi < 2; ++mi) {
#pragma unroll
      for (int ni = 0; ni < 2; ++ni) {
#pragma unroll
        for (int r = 0; r < 4; ++r) {
          int o = wo + mi * 16 + qr + r;
          int pw = w0 + wp + ni * 16 + col;
          out[((b * 64 + o) * 128 + h) * 128 + pw] = acc[mi][ni][r] + bias[o];
        }
      }
    }
  }
}

extern "C" void kernel_launch(void* const* d_in, const int* in_sizes, int n_in,
                              void* d_out, int out_size, void* d_ws,
                              size_t ws_size, hipStream_t stream) {
  const float* x = (const float*)d_in[0];       // (4,64,128,128)
  const float* ow = (const float*)d_in[1];      // (18,64,3,3)
  const float* ob = (const float*)d_in[2];      // (18,)
  const float* wt = (const float*)d_in[3];      // (64,64,3,3)
  const float* bias = (const float*)d_in[4];    // (64,)
  float* out = (float*)d_out;                   // (4,64,128,128)

  char* ws = (char*)d_ws;
  float* offs = (float*)ws;                          // 4,718,592 B
  __bf16* xt = (__bf16*)(ws + 4718592);              // 8,388,608 B
  __bf16* wb = (__bf16*)(ws + 4718592 + 8388608);    // 73,728 B
  __bf16* owb = (__bf16*)(ws + 4718592 + 8388608 + 73728);  // 36,864 B

  k_xt<<<512, 256, 0, stream>>>(x, xt);
  k_wprep<<<144, 256, 0, stream>>>(wt, wb);
  k_owprep<<<72, 256, 0, stream>>>(ow, owb);
  k_offset_mfma<<<1024, 256, 0, stream>>>(xt, owb, ob, offs);
  k_main<<<1024, 256, 0, stream>>>(xt, offs, wb, bias, out);
}